// Round 1
// baseline (2397.005 us; speedup 1.0000x reference)
//
#include <hip/hip_runtime.h>
#include <stdint.h>

// NAS LSTM controller on MI355X. H=2048, 8 categories, 2 cells x (2 warmup + 6 nodes).
// Sequential chain of 64 LSTM steps; exact JAX threefry RNG replication for sampling.

#define HDIM 2048
#define NCAT 8
#define PARTITIONABLE 1   // modern JAX (>=0.4.30) default threefry mode

// ---------------- threefry2x32 (20 rounds) ----------------
__device__ __forceinline__ unsigned rotl32(unsigned v, int r){ return (v<<r)|(v>>(32-r)); }

__device__ inline void tf_block(unsigned k0, unsigned k1, unsigned x0, unsigned x1,
                                unsigned& o0, unsigned& o1){
  unsigned ks0=k0, ks1=k1, ks2=0x1BD11BDAu ^ k0 ^ k1;
  const int ra[4]={13,15,26,6};
  const int rb[4]={17,29,16,24};
  x0 += ks0; x1 += ks1;
  #pragma unroll
  for (int i=0;i<4;++i){ x0+=x1; x1=rotl32(x1,ra[i]); x1^=x0; }
  x0+=ks1; x1+=ks2+1u;
  #pragma unroll
  for (int i=0;i<4;++i){ x0+=x1; x1=rotl32(x1,rb[i]); x1^=x0; }
  x0+=ks2; x1+=ks0+2u;
  #pragma unroll
  for (int i=0;i<4;++i){ x0+=x1; x1=rotl32(x1,ra[i]); x1^=x0; }
  x0+=ks0; x1+=ks1+3u;
  #pragma unroll
  for (int i=0;i<4;++i){ x0+=x1; x1=rotl32(x1,rb[i]); x1^=x0; }
  x0+=ks1; x1+=ks2+4u;
  #pragma unroll
  for (int i=0;i<4;++i){ x0+=x1; x1=rotl32(x1,ra[i]); x1^=x0; }
  x0+=ks2; x1+=ks0+5u;
  o0=x0; o1=x1;
}

__device__ __forceinline__ float sigm(float z){ return 1.0f/(1.0f+expf(-z)); }

// gumbel-argmax categorical + cross-entropy/entropy stats, exactly as reference.
__device__ inline int sample_and_stats(const float* logits, unsigned k0, unsigned k1,
                                       float* scal /* [ent, lp] */){
  unsigned bits[NCAT];
#if PARTITIONABLE
  #pragma unroll
  for (int i=0;i<NCAT;++i){ unsigned a,b; tf_block(k0,k1,0u,(unsigned)i,a,b); bits[i]=a^b; }
#else
  #pragma unroll
  for (int i=0;i<4;++i){ unsigned a,b; tf_block(k0,k1,(unsigned)i,(unsigned)(i+4),a,b); bits[i]=a; bits[i+4]=b; }
#endif
  const float tiny = 1.1754943508222875e-38f;
  int best=0; float bv=-3.4e38f;
  #pragma unroll
  for (int j=0;j<NCAT;++j){
    float f = __uint_as_float((bits[j]>>9)|0x3f800000u) - 1.0f;
    float u = fmaxf(tiny, f*(1.0f-tiny)+tiny);
    float g = -logf(-logf(u));
    float vv = g + logits[j];
    if (vv > bv){ bv=vv; best=j; }     // first-max wins, like jnp.argmax
  }
  float m=-3.4e38f;
  #pragma unroll
  for (int j=0;j<NCAT;++j) m = fmaxf(m, logits[j]);
  float se=0.f;
  #pragma unroll
  for (int j=0;j<NCAT;++j) se += expf(logits[j]-m);
  float lse = logf(se);
  scal[1] += (m + lse - logits[best]);            // lp += -logp[idx]
  float ent = 0.f;
  #pragma unroll
  for (int j=0;j<NCAT;++j){
    float lpj = logits[j]-m-lse;
    float p = expf(lpj);
    if (p > 0.f) ent -= p*lpj;                    // where(p>0, p*logp, 0)
  }
  scal[0] += ent;
  return best;
}

// ---------------- workspace layout (floats) ----------------
// 0: h0 | 2048: h1 | 4096: c | 6144: x | 8192: t2 | 10240: anchors(8x2048)
// 26624: anchors_w1(8x2048) | 43008: scal[ent,lp] | 43012: nodekeys (24 u32)

__global__ __launch_bounds__(256) void k_init(float* ws, const float* __restrict__ emb,
                                              const int* __restrict__ seedp, int cell){
  int t = threadIdx.x;
  float* anch = ws + 10240;
  float* aw1  = ws + 26624;
  for (int i=t;i<NCAT*HDIM;i+=256){ anch[i]=0.f; aw1[i]=0.f; }
  float* x = ws + 6144;
  for (int i=t;i<HDIM;i+=256){
    x[i] = emb[i];                       // x = emb[0]
    if (cell==0){ ws[i]=0.f; ws[4096+i]=0.f; }  // h0 = 0, c = 0 (cell 1 keeps hc)
  }
  if (t==0 && cell==0){
    float* scal = ws + 43008; scal[0]=0.f; scal[1]=0.f;
    unsigned* nk = (unsigned*)(ws + 43012);
    unsigned seed = (unsigned)seedp[0];
    unsigned K0=0u, K1=seed;            // jax.random.key(seed) -> (hi=0, lo=seed)
    unsigned ck[2][2];
#if PARTITIONABLE
    tf_block(K0,K1,0u,0u,ck[0][0],ck[0][1]);   // k1
    tf_block(K0,K1,0u,1u,ck[1][0],ck[1][1]);   // k2
    for (int cc=0;cc<2;++cc)
      for (int i=0;i<6;++i)
        tf_block(ck[cc][0],ck[cc][1],0u,(unsigned)i, nk[(cc*6+i)*2], nk[(cc*6+i)*2+1]);
#else
    unsigned a0,a1,b0,b1;
    tf_block(K0,K1,0u,2u,a0,a1);               // lanes (0,2),(1,3)
    tf_block(K0,K1,1u,3u,b0,b1);
    ck[0][0]=a0; ck[0][1]=b0; ck[1][0]=a1; ck[1][1]=b1;
    for (int cc=0;cc<2;++cc){
      unsigned y0[6], y1[6];
      for (int i=0;i<6;++i) tf_block(ck[cc][0],ck[cc][1],(unsigned)i,(unsigned)(i+6),y0[i],y1[i]);
      unsigned flat[12];
      for (int i=0;i<6;++i){ flat[i]=y0[i]; flat[6+i]=y1[i]; }
      for (int i=0;i<6;++i){ nk[(cc*6+i)*2]=flat[2*i]; nk[(cc*6+i)*2+1]=flat[2*i+1]; }
    }
#endif
  }
}

// Fused LSTM step: block b owns hidden units k0..k0+3; wave w computes the 4 rows of
// gate w (rows w*2048+k0..+3) of g = w_ih@x + w_hh@h + b; then pointwise c/h update.
// h double-buffered (h_in read by all blocks, h_out written only by owner block).
__global__ __launch_bounds__(256) void k_lstm(
    const float* __restrict__ w_ih, const float* __restrict__ w_hh,
    const float* __restrict__ b_ih, const float* __restrict__ b_hh,
    const float* __restrict__ x, const float* __restrict__ h_in,
    float* __restrict__ h_out, float* __restrict__ c)
{
  int b  = blockIdx.x;          // 0..511
  int k0 = b*4;
  int wv = threadIdx.x >> 6;    // gate 0..3 (i,f,g,o)
  int ln = threadIdx.x & 63;
  __shared__ float gl[4][4];
  const float4* x4 = (const float4*)x;
  const float4* h4 = (const float4*)h_in;
  float acc[4];
  #pragma unroll
  for (int rr=0; rr<4; ++rr){
    int row = wv*HDIM + k0 + rr;
    const float4* wi = (const float4*)(w_ih + (size_t)row*HDIM);
    const float4* wh = (const float4*)(w_hh + (size_t)row*HDIM);
    float s = 0.f;
    #pragma unroll
    for (int it=0; it<8; ++it){
      int i4 = ln + it*64;
      float4 a = wi[i4]; float4 xv = x4[i4];
      float4 bb = wh[i4]; float4 hv = h4[i4];
      s += a.x*xv.x + a.y*xv.y + a.z*xv.z + a.w*xv.w;
      s += bb.x*hv.x + bb.y*hv.y + bb.z*hv.z + bb.w*hv.w;
    }
    acc[rr] = s;
  }
  #pragma unroll
  for (int rr=0; rr<4; ++rr){
    float s = acc[rr];
    #pragma unroll
    for (int m=32; m; m>>=1) s += __shfl_xor(s, m, 64);
    if (ln==0) gl[wv][rr] = s;
  }
  __syncthreads();
  if (threadIdx.x < 4){
    int kk = k0 + threadIdx.x;
    float gi = gl[0][threadIdx.x] + b_ih[kk]          + b_hh[kk];
    float gf = gl[1][threadIdx.x] + b_ih[HDIM+kk]     + b_hh[HDIM+kk];
    float gg = gl[2][threadIdx.x] + b_ih[2*HDIM+kk]   + b_hh[2*HDIM+kk];
    float go = gl[3][threadIdx.x] + b_ih[3*HDIM+kk]   + b_hh[3*HDIM+kk];
    float cn = sigm(gf)*c[kk] + sigm(gi)*tanhf(gg);
    c[kk] = cn;
    h_out[kk] = sigm(go)*tanhf(cn);
  }
}

// 2048x2048 matvec: vout = M @ vin. Optional 8-elem/block copies:
// cdst=csrc (anchors[s]=h) and xdst=xsrc (x=emb[0]).
__global__ __launch_bounds__(256) void k_matvec(const float* __restrict__ M,
    const float* __restrict__ vin, float* __restrict__ vout,
    const float* __restrict__ csrc, float* __restrict__ cdst,
    const float* __restrict__ xsrc, float* __restrict__ xdst)
{
  int b = blockIdx.x;           // 0..255, 8 rows per block
  int wv = threadIdx.x>>6, ln = threadIdx.x&63;
  const float4* v4 = (const float4*)vin;
  #pragma unroll
  for (int rr=0; rr<2; ++rr){
    int row = b*8 + wv*2 + rr;
    const float4* m4 = (const float4*)(M + (size_t)row*HDIM);
    float s=0.f;
    #pragma unroll
    for (int it=0; it<8; ++it){
      int i4 = ln + it*64;
      float4 a = m4[i4]; float4 v = v4[i4];
      s += a.x*v.x + a.y*v.y + a.z*v.z + a.w*v.w;
    }
    #pragma unroll
    for (int m=32; m; m>>=1) s += __shfl_xor(s, m, 64);
    if (ln==0) vout[row] = s;
  }
  int t = threadIdx.x;
  if (t < 8){
    int i = b*8 + t;
    if (cdst) cdst[i] = csrc[i];
    if (xdst) xdst[i] = xsrc[i];
  }
}

// Attention scores + sample idx + x = anchors[idx]. One block, 8 waves (wave j = anchor j).
__global__ __launch_bounds__(512) void k_attn_sample(const float* __restrict__ t2,
    const float* __restrict__ aw1, const float* __restrict__ vatt,
    const float* __restrict__ anch, float* __restrict__ x, float* scal,
    const unsigned* __restrict__ nk, int cell, int node, int isub,
    float* __restrict__ outslot)
{
  __shared__ float sc[NCAT];
  __shared__ int sidx;
  int wv = threadIdx.x>>6, ln = threadIdx.x&63;
  const float* a = aw1 + (size_t)wv*HDIM;
  float s=0.f;
  for (int it=0; it<32; ++it){
    int d = ln + it*64;
    s += tanhf(t2[d] + a[d]) * vatt[d];
  }
  #pragma unroll
  for (int m=32; m; m>>=1) s += __shfl_xor(s, m, 64);
  if (ln==0) sc[wv]=s;
  __syncthreads();
  if (threadIdx.x==0){
    int svis = node + 2;
    float logits[NCAT];
    #pragma unroll
    for (int j=0;j<NCAT;++j) logits[j] = (j<svis)? sc[j] : -1e9f;
    unsigned f0,f1;
    tf_block(nk[(cell*6+node)*2], nk[(cell*6+node)*2+1], 0u, (unsigned)isub, f0, f1);
    int idx = sample_and_stats(logits, f0, f1, scal);
    *outslot = (float)idx;
    sidx = idx;
  }
  __syncthreads();
  const float* src = anch + (size_t)sidx*HDIM;
  for (int d=threadIdx.x; d<HDIM; d+=512) x[d]=src[d];
}

// Op logits + sample op + x = emb[op+1]. One block, wave j = op j.
__global__ __launch_bounds__(512) void k_opt_sample(const float* __restrict__ h,
    const float* __restrict__ wopt, const float* __restrict__ bopt,
    const float* __restrict__ emb, float* __restrict__ x, float* scal,
    const unsigned* __restrict__ nk, int cell, int node, int isub,
    float* __restrict__ outslot)
{
  __shared__ float sc[NCAT];
  __shared__ int sop;
  int wv = threadIdx.x>>6, ln = threadIdx.x&63;
  const float4* m4 = (const float4*)(wopt + (size_t)wv*HDIM);
  const float4* h4 = (const float4*)h;
  float s=0.f;
  #pragma unroll
  for (int it=0; it<8; ++it){
    int i4 = ln + it*64;
    float4 a = m4[i4]; float4 v = h4[i4];
    s += a.x*v.x + a.y*v.y + a.z*v.z + a.w*v.w;
  }
  #pragma unroll
  for (int m=32; m; m>>=1) s += __shfl_xor(s, m, 64);
  if (ln==0) sc[wv] = s + bopt[wv];
  __syncthreads();
  if (threadIdx.x==0){
    float logits[NCAT];
    #pragma unroll
    for (int j=0;j<NCAT;++j) logits[j]=sc[j];
    unsigned f0,f1;
    tf_block(nk[(cell*6+node)*2], nk[(cell*6+node)*2+1], 0u, (unsigned)(2+isub), f0, f1);
    int op = sample_and_stats(logits, f0, f1, scal);
    *outslot = (float)op;
    sop = op;
  }
  __syncthreads();
  const float* src = emb + (size_t)(sop+1)*HDIM;
  for (int d=threadIdx.x; d<HDIM; d+=512) x[d]=src[d];
}

__global__ void k_fin(const float* __restrict__ scal, float* __restrict__ out){
  out[48] = scal[0];   // ent_n + ent_r
  out[49] = scal[1];   // lp_n + lp_r
}

extern "C" void kernel_launch(void* const* d_in, const int* in_sizes, int n_in,
                              void* d_out, int out_size, void* d_ws, size_t ws_size,
                              hipStream_t stream)
{
  (void)in_sizes; (void)n_in; (void)out_size; (void)ws_size;
  const float* emb   = (const float*)d_in[0];
  const float* w_ih  = (const float*)d_in[1];
  const float* w_hh  = (const float*)d_in[2];
  const float* b_ih  = (const float*)d_in[3];
  const float* b_hh  = (const float*)d_in[4];
  const float* w_opt = (const float*)d_in[5];
  const float* b_opt = (const float*)d_in[6];
  const float* w1    = (const float*)d_in[7];   // w_attn1
  const float* w2    = (const float*)d_in[8];   // w_attn2
  const float* vatt  = (const float*)d_in[9];
  const int*   seed  = (const int*)d_in[10];

  float* ws  = (float*)d_ws;
  float* out = (float*)d_out;

  float* h[2] = { ws+0, ws+2048 };
  float* c    = ws+4096;
  float* x    = ws+6144;
  float* t2   = ws+8192;
  float* anch = ws+10240;
  float* aw1  = ws+26624;
  float* scal = ws+43008;
  const unsigned* nk = (const unsigned*)(ws+43012);

  int cur = 0;
  for (int cell=0; cell<2; ++cell){
    k_init<<<1,256,0,stream>>>(ws, emb, seed, cell);
    // warmup: 2 LSTM steps, anchors_w1[s] = w1 @ h (anchors stay zero)
    for (int s=0; s<2; ++s){
      k_lstm<<<512,256,0,stream>>>(w_ih,w_hh,b_ih,b_hh,x,h[cur],h[cur^1],c); cur^=1;
      k_matvec<<<256,256,0,stream>>>(w1, h[cur], aw1 + s*HDIM,
                                     nullptr,nullptr,nullptr,nullptr);
    }
    for (int node=0; node<6; ++node){
      for (int i=0;i<2;++i){
        k_lstm<<<512,256,0,stream>>>(w_ih,w_hh,b_ih,b_hh,x,h[cur],h[cur^1],c); cur^=1;
        k_matvec<<<256,256,0,stream>>>(w2, h[cur], t2, nullptr,nullptr,nullptr,nullptr);
        k_attn_sample<<<1,512,0,stream>>>(t2, aw1, vatt, anch, x, scal, nk, cell, node, i,
                                          out + cell*24 + node*2 + i);
      }
      for (int i=0;i<2;++i){
        k_lstm<<<512,256,0,stream>>>(w_ih,w_hh,b_ih,b_hh,x,h[cur],h[cur^1],c); cur^=1;
        k_opt_sample<<<1,512,0,stream>>>(h[cur], w_opt, b_opt, emb, x, scal, nk, cell, node, i,
                                         out + cell*24 + 12 + node*2 + i);
      }
      // trailing LSTM; anchors[s]=h, anchors_w1[s]=w1@h, x=emb[0]
      k_lstm<<<512,256,0,stream>>>(w_ih,w_hh,b_ih,b_hh,x,h[cur],h[cur^1],c); cur^=1;
      k_matvec<<<256,256,0,stream>>>(w1, h[cur], aw1 + (node+2)*HDIM,
                                     h[cur], anch + (node+2)*HDIM, emb, x);
    }
  }
  k_fin<<<1,1,0,stream>>>(scal, out);
}